// Round 13
// baseline (297.007 us; speedup 1.0000x reference)
//
#include <hip/hip_runtime.h>
#include <hip/hip_bf16.h>

// q = x@Wq^T*scale; k = y@Wk^T; v = y@Wv^T
// out = strict_lower(q@k^T) @ v  -- causal LINEAR attention:
//   out_t = q_t @ P_t + strict_tril(q_t k_t^T) @ v_t,  P_t = sum_{c<t} k_c^T v_c
//
// v17-resubmit (round 12 was GPUAcquisitionTimeout -- no data; kernel
// unchanged from round 11 submission):
//  * gemm binder hypothesis: 2 identical barrier-locked blocks/CU phase-lock
//    and collide on the L2->CU port during simultaneous stage phases.
//    Fix: MERGE q-block + kv-block -> ONE block per CU computing q,k,v for
//    its (m0,n0): stages x-tile + y-tile (fp32 2x32KB) + Wq/Wk/Wv (3x16KB)
//    = 112KB dynamic LDS (hipFuncSetAttribute); grid 256 = exactly 1/CU,
//    one round, balanced 96 MFMA/wave/step. Same FLOPs, same staged bytes,
//    same proven 0-conflict tile machinery -- only scheduling topology moves.
//  * hs_gemm / prefix_scan / out_gemm / convert_w: v16-exact.
// ws (bf16 elems): q[4M] k[4M] kT[4M] vT[4M] | Ht[16M] Pt[16M]
//   wq(->Sd)/wk/wv[1M x3].

typedef __bf16 bf16x8 __attribute__((ext_vector_type(8)));
typedef __bf16 bf16x4 __attribute__((ext_vector_type(4)));
typedef __bf16 bf16x2 __attribute__((ext_vector_type(2)));
typedef float f32x4 __attribute__((ext_vector_type(4)));

#define MFMA16(a, b, c) __builtin_amdgcn_mfma_f32_16x16x32_bf16(a, b, c, 0, 0, 0)

constexpr float SCALE = 0.04419417382415922f; // 1/sqrt(512)

__device__ __forceinline__ void ld16(const void* g, void* l) {
    __builtin_amdgcn_global_load_lds(
        (__attribute__((address_space(1))) void*)g,
        (__attribute__((address_space(3))) void*)l, 16, 0, 0);
}

// bf16 tile frag: data-chunk c (16B) of row r from [128][64] bf16 tile
// (128B rows, 8 slots), slot = c ^ (r&7).
__device__ __forceinline__ bf16x8 frag(const __bf16* base, int r, int c) {
    return *(const bf16x8*)((const char*)base + r * 128 + ((c ^ (r & 7)) * 16));
}

// fp32 tile frag: chunks c0,c0+1 (16B each = 4 floats) of row r from
// [128][64] fp32 tile (256B rows, 16 slots), slot = c ^ (r&15); cvt to bf16x8.
__device__ __forceinline__ bf16x8 fragA32(const float* base, int r, int c0) {
    const char* rowp = (const char*)base + r * 256;
    f32x4 a = *(const f32x4*)(rowp + ((c0 ^ (r & 15)) * 16));
    f32x4 b = *(const f32x4*)(rowp + (((c0 + 1) ^ (r & 15)) * 16));
    bf16x8 o;
    o[0] = (__bf16)a[0]; o[1] = (__bf16)a[1];
    o[2] = (__bf16)a[2]; o[3] = (__bf16)a[3];
    o[4] = (__bf16)b[0]; o[5] = (__bf16)b[1];
    o[6] = (__bf16)b[2]; o[7] = (__bf16)b[3];
    return o;
}

__device__ inline bf16x4 pack4(float4 a) {
    bf16x4 r;
    r[0] = (__bf16)a.x; r[1] = (__bf16)a.y;
    r[2] = (__bf16)a.z; r[3] = (__bf16)a.w;
    return r;
}

// ---------------------------------------------------------------------------
// Weights fp32 -> bf16 only. Wave owns 512 contiguous floats. 6144 waves.
// ---------------------------------------------------------------------------
__global__ __launch_bounds__(256) void convert_w(
    const float* __restrict__ wqf, const float* __restrict__ wkf,
    const float* __restrict__ wvf, __bf16* __restrict__ wqb,
    __bf16* __restrict__ wkb, __bf16* __restrict__ wvb)
{
    const size_t tid = (size_t)blockIdx.x * 256 + threadIdx.x;
    const size_t w = tid >> 6;
    const int lane = (int)(tid & 63);
    size_t f = w * 512;
    const float* src; __bf16* dst;
    if (f < 1048576)      { src = wqf; dst = wqb; }
    else if (f < 2097152) { src = wkf; dst = wkb; f -= 1048576; }
    else                  { src = wvf; dst = wvb; f -= 2097152; }
    const float4* s4 = (const float4*)(src + f);
    float4 a = s4[lane];
    float4 b = s4[64 + lane];
    __bf16* d = dst + f;
    *(bf16x4*)(d + lane * 4)       = pack4(a);
    *(bf16x4*)(d + 256 + lane * 4) = pack4(b);
}

// ---------------------------------------------------------------------------
// Merged q/k/v GEMM: ONE block per (m0, n0) computes all three outputs.
//   acc_q = bf16(x_t) @ Wq^T -> qo (SCALE folded)
//   acc_k = bf16(y_t) @ Wk^T -> ko + kT
//   acc_v = bf16(y_t) @ Wv^T -> vT
// 256 blocks = 1/CU, XCD-swizzled (8 m-tiles x 4 n per XCD). 112KB dynamic
// LDS: Ax,Ay fp32 [128][64] (16-slot swizzle) + Bq,Bk,Bv bf16 [128][64]
// (8-slot). One barrier domain: stage 112KB -> drain -> 96 MFMA/wave.
// ---------------------------------------------------------------------------
__global__ __launch_bounds__(256, 1) void gemm_qkv3(
    const float* __restrict__ x, const float* __restrict__ y,
    const __bf16* __restrict__ wq, const __bf16* __restrict__ wk,
    const __bf16* __restrict__ wv, __bf16* __restrict__ qo,
    __bf16* __restrict__ ko, __bf16* __restrict__ kT,
    __bf16* __restrict__ vT)
{
    constexpr int K = 2048, N = 512;
    extern __shared__ char smem[];
    float*  Ax = (float*)smem;                      // [128][64] f32, 32 KB
    float*  Ay = (float*)(smem + 32768);            // 32 KB
    __bf16* Bq = (__bf16*)(smem + 65536);           // [128][64] bf16, 16 KB
    __bf16* Bk = (__bf16*)(smem + 81920);           // 16 KB
    __bf16* Bv = (__bf16*)(smem + 98304);           // 16 KB -> 112 KB total

    // XCD-aware remap (bijective on 256 blocks; lin%8 = XCD)
    const int lin = blockIdx.y * 64 + blockIdx.x;
    const int xcd = lin & 7, idx = lin >> 3;
    const int m0 = (xcd * 8 + (idx & 7)) * 128;
    const int n0 = (idx >> 3) * 128;

    const int tid  = threadIdx.x;
    const int wave = tid >> 6, lane = tid & 63;
    const int fr = lane & 15, fq = lane >> 4;
    const int wr = (wave >> 1) * 64, wc = (wave & 1) * 64;
    const int lr = lane >> 3;            // B staging: row within 8-row group
    const int cd = (lane & 7) ^ lr;      // B staging: swizzled chunk
    const int lr4 = lane >> 4;           // A staging: row within 4-row group
    const int cl  = lane & 15;           // A staging: LDS slot (16 per row)

    f32x4 aq[4][4], ak[4][4], av[4][4];
#pragma unroll
    for (int a = 0; a < 4; ++a)
#pragma unroll
        for (int b = 0; b < 4; ++b) {
            aq[a][b] = f32x4{0.f, 0.f, 0.f, 0.f};
            ak[a][b] = f32x4{0.f, 0.f, 0.f, 0.f};
            av[a][b] = f32x4{0.f, 0.f, 0.f, 0.f};
        }

    const float*  agx = x  + (size_t)(m0 + wave * 32 + lr4) * K;
    const float*  agy = y  + (size_t)(m0 + wave * 32 + lr4) * K;
    const __bf16* bgq = wq + (size_t)(n0 + wave * 32 + lr) * K + cd * 8;
    const __bf16* bgk = wk + (size_t)(n0 + wave * 32 + lr) * K + cd * 8;
    const __bf16* bgv = wv + (size_t)(n0 + wave * 32 + lr) * K + cd * 8;
    float*  axl = Ax + wave * 2048;      // wave's 32 rows x 64 f32
    float*  ayl = Ay + wave * 2048;
    __bf16* bql = Bq + wave * 2048;      // wave's 32 rows x 64 bf16
    __bf16* bkl = Bk + wave * 2048;
    __bf16* bvl = Bv + wave * 2048;

    for (int kk = 0; kk < K; kk += 64) {
        __syncthreads();                 // prev step's frag reads done
#pragma unroll
        for (int u = 0; u < 4; ++u) {
            ld16(bgq + (size_t)(u * 8) * K + kk, bql + u * 512);
            ld16(bgk + (size_t)(u * 8) * K + kk, bkl + u * 512);
            ld16(bgv + (size_t)(u * 8) * K + kk, bvl + u * 512);
        }
#pragma unroll
        for (int u = 0; u < 8; ++u) {
            const int rw = u * 4 + lr4;          // row within wave group
            const int c  = cl ^ (rw & 15);       // source data chunk
            ld16(agx + (size_t)(u * 4) * K + kk + c * 4, axl + u * 256);
            ld16(agy + (size_t)(u * 4) * K + kk + c * 4, ayl + u * 256);
        }
        __syncthreads();                 // drains vmcnt: tiles visible
#pragma unroll
        for (int ks = 0; ks < 2; ++ks) {
            bf16x8 fx[4], fy[4], bq_[4], bk_[4], bv_[4];
#pragma unroll
            for (int rt = 0; rt < 4; ++rt) {
                fx[rt] = fragA32(Ax, wr + rt * 16 + fr, ks * 8 + fq * 2);
                fy[rt] = fragA32(Ay, wr + rt * 16 + fr, ks * 8 + fq * 2);
            }
#pragma unroll
            for (int nt = 0; nt < 4; ++nt) {
                bq_[nt] = frag(Bq, wc + nt * 16 + fr, ks * 4 + fq);
                bk_[nt] = frag(Bk, wc + nt * 16 + fr, ks * 4 + fq);
                bv_[nt] = frag(Bv, wc + nt * 16 + fr, ks * 4 + fq);
            }
#pragma unroll
            for (int rt = 0; rt < 4; ++rt)
#pragma unroll
                for (int nt = 0; nt < 4; ++nt) {
                    aq[rt][nt] = MFMA16(fx[rt], bq_[nt], aq[rt][nt]);
                    ak[rt][nt] = MFMA16(fy[rt], bk_[nt], ak[rt][nt]);
                    av[rt][nt] = MFMA16(fy[rt], bv_[nt], av[rt][nt]);
                }
        }
    }

#pragma unroll
    for (int rt = 0; rt < 4; ++rt)
#pragma unroll
        for (int nt = 0; nt < 4; ++nt) {
            const int col  = n0 + wc + nt * 16 + fr;
            const int row0 = m0 + wr + rt * 16 + fq * 4;
            bf16x4 k4, v4;
#pragma unroll
            for (int r = 0; r < 4; ++r) {
                qo[(size_t)(row0 + r) * N + col] = (__bf16)(aq[rt][nt][r] * SCALE);
                k4[r] = (__bf16)ak[rt][nt][r];
                v4[r] = (__bf16)av[rt][nt][r];
                ko[(size_t)(row0 + r) * N + col] = k4[r];
            }
            *(bf16x4*)(kT + (size_t)col * 8192 + row0) = k4;
            *(bf16x4*)(vT + (size_t)col * 8192 + row0) = v4;
        }
}

// ---------------------------------------------------------------------------
// Merged H + diagonal-S launch (v13-exact), grid (16, 67):
//  y <  63: Ht[c][n][d] = (vT_c @ kT_c^T), c = y, K=128
//  y >= 63: Sd[t] = strict_tril(q_t @ k_t^T), t = (y-63)*16 + x, K=512
// ---------------------------------------------------------------------------
__global__ __launch_bounds__(256, 3) void hs_gemm(
    const __bf16* __restrict__ vT, const __bf16* __restrict__ kT,
    const __bf16* __restrict__ q, const __bf16* __restrict__ k,
    __bf16* __restrict__ Ht, __bf16* __restrict__ Sd)
{
    __shared__ __align__(16) __bf16 As[128][64];
    __shared__ __align__(16) __bf16 Bs[128][64];

    const int tid  = threadIdx.x;
    const int wave = tid >> 6, lane = tid & 63;
    const int fr = lane & 15, fq = lane >> 4;
    const int wr = (wave >> 1) * 64, wc = (wave & 1) * 64;
    const int lr = lane >> 3;
    const int cd = (lane & 7) ^ lr;

    f32x4 acc[4][4];
#pragma unroll
    for (int a = 0; a < 4; ++a)
#pragma unroll
        for (int b = 0; b < 4; ++b) acc[a][b] = f32x4{0.f, 0.f, 0.f, 0.f};

    __bf16* al = &As[wave * 32][0];
    __bf16* bl = &Bs[wave * 32][0];

    if (blockIdx.y < 63) {
        const int c  = blockIdx.y;
        const int m0 = (blockIdx.x & 3) * 128;
        const int n0 = (blockIdx.x >> 2) * 128;

        const __bf16* ag = vT + (size_t)(m0 + wave * 32 + lr) * 8192 + c * 128 + cd * 8;
        const __bf16* bg = kT + (size_t)(n0 + wave * 32 + lr) * 8192 + c * 128 + cd * 8;

        for (int kk = 0; kk < 128; kk += 64) {
            __syncthreads();
#pragma unroll
            for (int u = 0; u < 4; ++u) {
                ld16(ag + (size_t)(u * 8) * 8192 + kk, al + u * 512);
                ld16(bg + (size_t)(u * 8) * 8192 + kk, bl + u * 512);
            }
            __syncthreads();
#pragma unroll
            for (int ks = 0; ks < 2; ++ks) {
                bf16x8 af[4], bf[4];
#pragma unroll
                for (int rt = 0; rt < 4; ++rt)
                    af[rt] = frag(&As[0][0], wr + rt * 16 + fr, ks * 4 + fq);
#pragma unroll
                for (int nt = 0; nt < 4; ++nt)
                    bf[nt] = frag(&Bs[0][0], wc + nt * 16 + fr, ks * 4 + fq);
#pragma unroll
                for (int rt = 0; rt < 4; ++rt)
#pragma unroll
                    for (int nt = 0; nt < 4; ++nt)
                        acc[rt][nt] = MFMA16(af[rt], bf[nt], acc[rt][nt]);
            }
        }

        __bf16* tp = Ht + (size_t)c * 262144;
#pragma unroll
        for (int rt = 0; rt < 4; ++rt)
#pragma unroll
            for (int nt = 0; nt < 4; ++nt) {
                const int col = n0 + wc + nt * 16 + fr;
#pragma unroll
                for (int r = 0; r < 4; ++r) {
                    const int row = m0 + wr + rt * 16 + fq * 4 + r;
                    tp[(size_t)row * 512 + col] = (__bf16)acc[rt][nt][r];
                }
            }
    } else {
        const int t = (blockIdx.y - 63) * 16 + blockIdx.x;

        const __bf16* ag = q + (size_t)(t * 128 + wave * 32 + lr) * 512 + cd * 8;
        const __bf16* bg = k + (size_t)(t * 128 + wave * 32 + lr) * 512 + cd * 8;

        for (int kk = 0; kk < 512; kk += 64) {
            __syncthreads();
#pragma unroll
            for (int u = 0; u < 4; ++u) {
                ld16(ag + (size_t)(u * 8) * 512 + kk, al + u * 512);
                ld16(bg + (size_t)(u * 8) * 512 + kk, bl + u * 512);
            }
            __syncthreads();
#pragma unroll
            for (int ks = 0; ks < 2; ++ks) {
                bf16x8 af[4], bf[4];
#pragma unroll
                for (int rt = 0; rt < 4; ++rt)
                    af[rt] = frag(&As[0][0], wr + rt * 16 + fr, ks * 4 + fq);
#pragma unroll
                for (int nt = 0; nt < 4; ++nt)
                    bf[nt] = frag(&Bs[0][0], wc + nt * 16 + fr, ks * 4 + fq);
#pragma unroll
                for (int rt = 0; rt < 4; ++rt)
#pragma unroll
                    for (int nt = 0; nt < 4; ++nt)
                        acc[rt][nt] = MFMA16(af[rt], bf[nt], acc[rt][nt]);
            }
        }

        __bf16* tp = Sd + (size_t)t * 16384;
#pragma unroll
        for (int rt = 0; rt < 4; ++rt)
#pragma unroll
            for (int nt = 0; nt < 4; ++nt) {
                const int col = wc + nt * 16 + fr;
#pragma unroll
                for (int r = 0; r < 4; ++r) {
                    const int row = wr + rt * 16 + fq * 4 + r;
                    float vv = (col < row) ? acc[rt][nt][r] : 0.f;
                    tp[row * 128 + col] = (__bf16)vv;
                }
            }
    }
}

// ---------------------------------------------------------------------------
// Exclusive prefix over chunk axis: Pt[c] = sum_{c'<c} Ht[c'], fp32 accum.
// 512 blocks x 256 thr, 2 elems/thread (v13-exact).
// ---------------------------------------------------------------------------
__global__ __launch_bounds__(256) void prefix_scan(
    const __bf16* __restrict__ Ht, __bf16* __restrict__ Pt)
{
    const size_t e = ((size_t)blockIdx.x * 256 + threadIdx.x) * 2;
    float a0 = 0.f, a1 = 0.f;
#pragma unroll 9
    for (int c = 0; c < 63; ++c) {
        bf16x2 h = *(const bf16x2*)(Ht + (size_t)c * 262144 + e);
        a0 += (float)h[0]; a1 += (float)h[1];
        bf16x2 p;
        p[0] = (__bf16)a0; p[1] = (__bf16)a1;
        *(bf16x2*)(Pt + (size_t)(c + 1) * 262144 + e) = p;
    }
}

// ---------------------------------------------------------------------------
// Out kernel (v13-exact), block (t, n0):
// Phase B: acc = q_t @ Pt_t (K=512, skipped for t=0)
// Phase C: acc += Sd[t] @ v_t (K=128, both operands staged via ld16)
// Non-atomic fp32 store (block owns its 128x128 tile).
// ---------------------------------------------------------------------------
__global__ __launch_bounds__(256, 3) void out_gemm(
    const __bf16* __restrict__ q, const __bf16* __restrict__ Sd,
    const __bf16* __restrict__ vT, const __bf16* __restrict__ Pt,
    float* __restrict__ out)
{
    __shared__ __align__(16) __bf16 As[128][64];
    __shared__ __align__(16) __bf16 Bs[128][64];

    const int t  = blockIdx.x;
    const int n0 = blockIdx.y * 128;

    const int tid  = threadIdx.x;
    const int wave = tid >> 6, lane = tid & 63;
    const int fr = lane & 15, fq = lane >> 4;
    const int wr = (wave >> 1) * 64, wc = (wave & 1) * 64;
    const int lr = lane >> 3;
    const int cd = (lane & 7) ^ lr;
    const int srow = wave * 32 + lr;

    f32x4 acc[4][4];
#pragma unroll
    for (int a = 0; a < 4; ++a)
#pragma unroll
        for (int b = 0; b < 4; ++b) acc[a][b] = f32x4{0.f, 0.f, 0.f, 0.f};

    __bf16* al = &As[wave * 32][0];
    __bf16* bl = &Bs[wave * 32][0];

    // ---- Phase B: inter, acc = q_t @ Pt_t, K=512 ----
    if (t > 0) {
        const __bf16* ag = q + (size_t)(t * 128 + srow) * 512 + cd * 8;
        const __bf16* bg2 = Pt + (size_t)t * 262144
                          + (size_t)(n0 + srow) * 512 + cd * 8;
        for (int kk = 0; kk < 512; kk += 64) {
            __syncthreads();
#pragma unroll
            for (int u = 0; u < 4; ++u) {
                ld16(ag + (size_t)(u * 8) * 512 + kk, al + u * 512);
                ld16(bg2 + (size_t)(u * 8) * 512 + kk, bl + u * 512);
            }
            __syncthreads();
#pragma unroll
            for (int ks = 0; ks < 2; ++ks) {
                bf16x8 af[4], bf[4];
#pragma unroll
                for (int rt = 0; rt < 4; ++rt)
                    af[rt] = frag(&As[0][0], wr + rt * 16 + fr, ks * 4 + fq);
#pragma unroll
                for (int nt = 0; nt < 4; ++nt)
                    bf[nt] = frag(&Bs[0][0], wc + nt * 16 + fr, ks * 4 + fq);
#pragma unroll
                for (int rt = 0; rt < 4; ++rt)
#pragma unroll
                    for (int nt = 0; nt < 4; ++nt)
                        acc[rt][nt] = MFMA16(af[rt], bf[nt], acc[rt][nt]);
            }
        }
    }

    // ---- Phase C: acc += Sd[t] @ v_t, K=128 (both staged via ld16) ----
    const __bf16* at3 = Sd + (size_t)t * 16384 + (size_t)srow * 128 + cd * 8;
    const __bf16* bg3 = vT + (size_t)(n0 + srow) * 8192 + t * 128 + cd * 8;
    for (int kk = 0; kk < 128; kk += 64) {
        __syncthreads();
#pragma unroll
        for (int u = 0; u < 4; ++u) {
            ld16(at3 + (size_t)(u * 8) * 128 + kk, al + u * 512);
            ld16(bg3 + (size_t)(u * 8) * 8192 + kk, bl + u * 512);
        }
        __syncthreads();
#pragma unroll
        for (int ks = 0; ks < 2; ++ks) {
            bf16x8 af[4], bf[4];
#pragma unroll
            for (int rt = 0; rt < 4; ++rt)
                af[rt] = frag(&As[0][0], wr + rt * 16 + fr, ks * 4 + fq);
#pragma unroll
            for (int nt = 0; nt < 4; ++nt)
                bf[nt] = frag(&Bs[0][0], wc + nt * 16 + fr, ks * 4 + fq);
#pragma unroll
            for (int rt = 0; rt < 4; ++rt)
#pragma unroll
                for (int nt = 0; nt < 4; ++nt)
                    acc[rt][nt] = MFMA16(af[rt], bf[nt], acc[rt][nt]);
        }
    }

    // epilogue: exclusive owner of this 128x128 tile -> plain fp32 store
#pragma unroll
    for (int rt = 0; rt < 4; ++rt)
#pragma unroll
        for (int nt = 0; nt < 4; ++nt) {
            const int col = n0 + wc + nt * 16 + fr;
#pragma unroll
            for (int r = 0; r < 4; ++r) {
                const int row = t * 128 + wr + rt * 16 + fq * 4 + r;
                out[(size_t)row * 512 + col] = acc[rt][nt][r];
            }
        }
}

// ---------------------------------------------------------------------------
extern "C" void kernel_launch(void* const* d_in, const int* in_sizes, int n_in,
                              void* d_out, int out_size, void* d_ws, size_t ws_size,
                              hipStream_t stream) {
    const float* x  = (const float*)d_in[0];
    const float* y  = (const float*)d_in[1];
    const float* Wq = (const float*)d_in[2];
    const float* Wk = (const float*)d_in[3];
    const float* Wv = (const float*)d_in[4];
    float* out = (float*)d_out;

    const size_t QK = (size_t)8192 * 512;       // 4194304
    __bf16* q  = (__bf16*)d_ws;
    __bf16* k  = q + QK;
    __bf16* kT = k + QK;
    __bf16* vT = kT + QK;
    __bf16* Ht  = vT + QK;                      // 16777216-elem region
    __bf16* Pt  = Ht + 16777216;                // 16777216-elem region
    __bf16* wqb = Pt + 16777216;
    __bf16* wkb = wqb + 1048576;
    __bf16* wvb = wkb + 1048576;
    __bf16* Sd = wqb;                           // alias: wqb dead after gemm

    const int smem = 114688;                    // 112 KB dynamic LDS
    static bool attr_done = false;
    if (!attr_done) {
        hipFuncSetAttribute((const void*)gemm_qkv3,
                            hipFuncAttributeMaxDynamicSharedMemorySize, smem);
        attr_done = true;
    }

    convert_w<<<1536, 256, 0, stream>>>(Wq, Wk, Wv, wqb, wkb, wvb);
    gemm_qkv3<<<dim3(64, 4), 256, smem, stream>>>(x, y, wqb, wkb, wvb, q, k, kT, vT);
    hs_gemm<<<dim3(16, 67), 256, 0, stream>>>(vT, kT, q, k, Ht, Sd);
    prefix_scan<<<512, 256, 0, stream>>>(Ht, Pt);
    out_gemm<<<dim3(64, 4), 256, 0, stream>>>(q, Sd, vT, Pt, out);
}

// Round 14
// 256.226 us; speedup vs baseline: 1.1592x; 1.1592x over previous
//
#include <hip/hip_runtime.h>
#include <hip/hip_bf16.h>

// q = x@Wq^T*scale; k = y@Wk^T; v = y@Wv^T
// out = strict_lower(q@k^T) @ v  -- causal LINEAR attention:
//   out_t = q_t @ P_t + strict_tril(q_t k_t^T) @ v_t,  P_t = sum_{c<t} k_c^T v_c
//
// v18 (from v17 @ 297 regression; best = v16 @ 251.0us):
//  * v17 falsified phase-collision but QUANTIFIED the real lever: runnable
//    waves/SIMD (1 -> 141us, 2 -> 94us). v18 doubles TLP at constant
//    everything-else: gemm blocks go 256 -> 512 threads (8 waves), same
//    BM=128 tile, same 64KB LDS, still 2 blocks/CU -> 4 waves/SIMD.
//    Per-wave work halves (acc [2][4]; A 4 issues, B 2 issues/tile).
//    Staging invariants re-derived: A chunk c = (l&15)^((w&3)*4+(l>>4));
//    B chunk c = (l&7)^(l>>3) (unchanged). XCD swizzle kept.
//  * hs_gemm / prefix_scan / out_gemm / convert_w: v16-exact.
// ws (bf16 elems): q[4M] k[4M] kT[4M] vT[4M] | Ht[16M] Pt[16M]
//   wq(->Sd)/wk/wv[1M x3].

typedef __bf16 bf16x8 __attribute__((ext_vector_type(8)));
typedef __bf16 bf16x4 __attribute__((ext_vector_type(4)));
typedef __bf16 bf16x2 __attribute__((ext_vector_type(2)));
typedef float f32x4 __attribute__((ext_vector_type(4)));

#define MFMA16(a, b, c) __builtin_amdgcn_mfma_f32_16x16x32_bf16(a, b, c, 0, 0, 0)

constexpr float SCALE = 0.04419417382415922f; // 1/sqrt(512)

__device__ __forceinline__ void ld16(const void* g, void* l) {
    __builtin_amdgcn_global_load_lds(
        (__attribute__((address_space(1))) void*)g,
        (__attribute__((address_space(3))) void*)l, 16, 0, 0);
}

// bf16 tile frag: data-chunk c (16B) of row r from [128][64] bf16 tile
// (128B rows, 8 slots), slot = c ^ (r&7).
__device__ __forceinline__ bf16x8 frag(const __bf16* base, int r, int c) {
    return *(const bf16x8*)((const char*)base + r * 128 + ((c ^ (r & 7)) * 16));
}

// fp32 tile frag: chunks c0,c0+1 (16B each = 4 floats) of row r from
// [128][64] fp32 tile (256B rows, 16 slots), slot = c ^ (r&15); cvt to bf16x8.
__device__ __forceinline__ bf16x8 fragA32(const float* base, int r, int c0) {
    const char* rowp = (const char*)base + r * 256;
    f32x4 a = *(const f32x4*)(rowp + ((c0 ^ (r & 15)) * 16));
    f32x4 b = *(const f32x4*)(rowp + (((c0 + 1) ^ (r & 15)) * 16));
    bf16x8 o;
    o[0] = (__bf16)a[0]; o[1] = (__bf16)a[1];
    o[2] = (__bf16)a[2]; o[3] = (__bf16)a[3];
    o[4] = (__bf16)b[0]; o[5] = (__bf16)b[1];
    o[6] = (__bf16)b[2]; o[7] = (__bf16)b[3];
    return o;
}

__device__ inline bf16x4 pack4(float4 a) {
    bf16x4 r;
    r[0] = (__bf16)a.x; r[1] = (__bf16)a.y;
    r[2] = (__bf16)a.z; r[3] = (__bf16)a.w;
    return r;
}

// ---------------------------------------------------------------------------
// Weights fp32 -> bf16 only. Wave owns 512 contiguous floats. 6144 waves.
// ---------------------------------------------------------------------------
__global__ __launch_bounds__(256) void convert_w(
    const float* __restrict__ wqf, const float* __restrict__ wkf,
    const float* __restrict__ wvf, __bf16* __restrict__ wqb,
    __bf16* __restrict__ wkb, __bf16* __restrict__ wvb)
{
    const size_t tid = (size_t)blockIdx.x * 256 + threadIdx.x;
    const size_t w = tid >> 6;
    const int lane = (int)(tid & 63);
    size_t f = w * 512;
    const float* src; __bf16* dst;
    if (f < 1048576)      { src = wqf; dst = wqb; }
    else if (f < 2097152) { src = wkf; dst = wkb; f -= 1048576; }
    else                  { src = wvf; dst = wvb; f -= 2097152; }
    const float4* s4 = (const float4*)(src + f);
    float4 a = s4[lane];
    float4 b = s4[64 + lane];
    __bf16* d = dst + f;
    *(bf16x4*)(d + lane * 4)       = pack4(a);
    *(bf16x4*)(d + 256 + lane * 4) = pack4(b);
}

// ---------------------------------------------------------------------------
// Fused q/kv GEMM, 512 threads (8 waves), BM=128, 2 blocks/CU -> 4 waves/SIMD.
// 512 blocks, XCD-swizzled; ycfg even = q-block, odd = kv-block (dual B).
// A staged raw fp32 async into [128][64] f32 (16-slot swizzle); fp32->bf16
// at frag-read. B staged bf16 (8-slot). 64KB LDS.
// Wave layout: wr = (wave>>1)*32 (4 row-bands), wc = (wave&1)*64.
// A staging: wave w issue u covers rows (u*8+w)*4 + (l>>4), slot l&15,
//   src chunk c = (l&15) ^ ((w&3)*4 + (l>>4))  [row&15 is issue-invariant].
// B staging: wave w issue u covers rows (u*8+w)*8 + (l>>3), slot l&7,
//   src chunk c = (l&7) ^ (l>>3).
// ---------------------------------------------------------------------------
__global__ __launch_bounds__(512, 4) void gemm_qkv2(
    const float* __restrict__ x, const float* __restrict__ y,
    const __bf16* __restrict__ wq, const __bf16* __restrict__ wk,
    const __bf16* __restrict__ wv, __bf16* __restrict__ qo,
    __bf16* __restrict__ ko, __bf16* __restrict__ kT,
    __bf16* __restrict__ vT)
{
    constexpr int K = 2048, N = 512;
    __shared__ __align__(16) float  Asf[128][64];     // 32 KB
    __shared__ __align__(16) __bf16 Bs[2][128][64];   // 32 KB

    // XCD-aware remap (bijective on 512 blocks; lin%8 = XCD)
    const int lin  = blockIdx.y * 64 + blockIdx.x;
    const int xcd  = lin & 7;
    const int idx  = lin >> 3;
    const int mb   = xcd * 8 + (idx & 7);   // m-tile 0..63
    const int ycfg = idx >> 3;              // 0..7

    const bool iskv = (ycfg & 1) != 0;
    const float* A = iskv ? y : x;
    const __bf16* B0 = iskv ? wk : wq;

    const int tid  = threadIdx.x;
    const int wave = tid >> 6, lane = tid & 63;
    const int fr = lane & 15, fq = lane >> 4;
    const int m0 = mb * 128, n0 = (ycfg >> 1) * 128;
    const int wr = (wave >> 1) * 32, wc = (wave & 1) * 64;
    // B staging invariants
    const int lrB = lane >> 3;                 // row within 8-row group
    const int cB  = (lane & 7) ^ lrB;          // source chunk
    // A staging invariants
    const int lrA = lane >> 4;                 // row within 4-row group
    const int cA  = (lane & 15) ^ ((wave & 3) * 4 + lrA);

    f32x4 acc0[2][4], acc1[2][4];
#pragma unroll
    for (int a = 0; a < 2; ++a)
#pragma unroll
        for (int b = 0; b < 4; ++b) {
            acc0[a][b] = f32x4{0.f, 0.f, 0.f, 0.f};
            acc1[a][b] = f32x4{0.f, 0.f, 0.f, 0.f};
        }

    for (int kk = 0; kk < K; kk += 64) {
        __syncthreads();                 // prev step's frag reads done
        // B0 (and B1 for kv): 2 issues/lane per tile
#pragma unroll
        for (int u = 0; u < 2; ++u) {
            const int jb = u * 8 + wave;             // 8-row block 0..15
            const int rB = jb * 8 + lrB;             // row 0..127
            ld16(B0 + (size_t)(n0 + rB) * K + kk + cB * 8,
                 &Bs[0][jb * 8][0] + lane * 8);
        }
        if (iskv) {
#pragma unroll
            for (int u = 0; u < 2; ++u) {
                const int jb = u * 8 + wave;
                const int rB = jb * 8 + lrB;
                ld16(wv + (size_t)(n0 + rB) * K + kk + cB * 8,
                     &Bs[1][jb * 8][0] + lane * 8);
            }
        }
        // A: 4 issues/lane
#pragma unroll
        for (int u = 0; u < 4; ++u) {
            const int ja = u * 8 + wave;             // 4-row block 0..31
            const int rA = ja * 4 + lrA;             // row 0..127
            ld16(A + (size_t)(m0 + rA) * K + kk + cA * 4,
                 &Asf[ja * 4][0] + lane * 4);
        }
        __syncthreads();                 // drains vmcnt: tiles visible
#pragma unroll
        for (int ks = 0; ks < 2; ++ks) {
            bf16x8 af[2], bf[4];
#pragma unroll
            for (int rt = 0; rt < 2; ++rt)
                af[rt] = fragA32(&Asf[0][0], wr + rt * 16 + fr, ks * 8 + fq * 2);
#pragma unroll
            for (int nt = 0; nt < 4; ++nt)
                bf[nt] = frag(&Bs[0][0][0], wc + nt * 16 + fr, ks * 4 + fq);
#pragma unroll
            for (int rt = 0; rt < 2; ++rt)
#pragma unroll
                for (int nt = 0; nt < 4; ++nt)
                    acc0[rt][nt] = MFMA16(af[rt], bf[nt], acc0[rt][nt]);
            if (iskv) {
                bf16x8 bg[4];
#pragma unroll
                for (int nt = 0; nt < 4; ++nt)
                    bg[nt] = frag(&Bs[1][0][0], wc + nt * 16 + fr, ks * 4 + fq);
#pragma unroll
                for (int rt = 0; rt < 2; ++rt)
#pragma unroll
                    for (int nt = 0; nt < 4; ++nt)
                        acc1[rt][nt] = MFMA16(af[rt], bg[nt], acc1[rt][nt]);
            }
        }
    }

    if (!iskv) {
#pragma unroll
        for (int rt = 0; rt < 2; ++rt)
#pragma unroll
            for (int nt = 0; nt < 4; ++nt) {
                const int col = n0 + wc + nt * 16 + fr;
#pragma unroll
                for (int r = 0; r < 4; ++r) {
                    const int row = m0 + wr + rt * 16 + fq * 4 + r;
                    qo[(size_t)row * N + col] = (__bf16)(acc0[rt][nt][r] * SCALE);
                }
            }
    } else {
#pragma unroll
        for (int rt = 0; rt < 2; ++rt)
#pragma unroll
            for (int nt = 0; nt < 4; ++nt) {
                const int col  = n0 + wc + nt * 16 + fr;
                const int row0 = m0 + wr + rt * 16 + fq * 4;
                bf16x4 k4, v4;
#pragma unroll
                for (int r = 0; r < 4; ++r) {
                    k4[r] = (__bf16)acc0[rt][nt][r];
                    v4[r] = (__bf16)acc1[rt][nt][r];
                    ko[(size_t)(row0 + r) * N + col] = k4[r];
                }
                *(bf16x4*)(kT + (size_t)col * 8192 + row0) = k4;
                *(bf16x4*)(vT + (size_t)col * 8192 + row0) = v4;
            }
    }
}

// ---------------------------------------------------------------------------
// Merged H + diagonal-S launch (v13-exact), grid (16, 67):
//  y <  63: Ht[c][n][d] = (vT_c @ kT_c^T), c = y, K=128
//  y >= 63: Sd[t] = strict_tril(q_t @ k_t^T), t = (y-63)*16 + x, K=512
// ---------------------------------------------------------------------------
__global__ __launch_bounds__(256, 3) void hs_gemm(
    const __bf16* __restrict__ vT, const __bf16* __restrict__ kT,
    const __bf16* __restrict__ q, const __bf16* __restrict__ k,
    __bf16* __restrict__ Ht, __bf16* __restrict__ Sd)
{
    __shared__ __align__(16) __bf16 As[128][64];
    __shared__ __align__(16) __bf16 Bs[128][64];

    const int tid  = threadIdx.x;
    const int wave = tid >> 6, lane = tid & 63;
    const int fr = lane & 15, fq = lane >> 4;
    const int wr = (wave >> 1) * 64, wc = (wave & 1) * 64;
    const int lr = lane >> 3;
    const int cd = (lane & 7) ^ lr;

    f32x4 acc[4][4];
#pragma unroll
    for (int a = 0; a < 4; ++a)
#pragma unroll
        for (int b = 0; b < 4; ++b) acc[a][b] = f32x4{0.f, 0.f, 0.f, 0.f};

    __bf16* al = &As[wave * 32][0];
    __bf16* bl = &Bs[wave * 32][0];

    if (blockIdx.y < 63) {
        const int c  = blockIdx.y;
        const int m0 = (blockIdx.x & 3) * 128;
        const int n0 = (blockIdx.x >> 2) * 128;

        const __bf16* ag = vT + (size_t)(m0 + wave * 32 + lr) * 8192 + c * 128 + cd * 8;
        const __bf16* bg = kT + (size_t)(n0 + wave * 32 + lr) * 8192 + c * 128 + cd * 8;

        for (int kk = 0; kk < 128; kk += 64) {
            __syncthreads();
#pragma unroll
            for (int u = 0; u < 4; ++u) {
                ld16(ag + (size_t)(u * 8) * 8192 + kk, al + u * 512);
                ld16(bg + (size_t)(u * 8) * 8192 + kk, bl + u * 512);
            }
            __syncthreads();
#pragma unroll
            for (int ks = 0; ks < 2; ++ks) {
                bf16x8 af[4], bf[4];
#pragma unroll
                for (int rt = 0; rt < 4; ++rt)
                    af[rt] = frag(&As[0][0], wr + rt * 16 + fr, ks * 4 + fq);
#pragma unroll
                for (int nt = 0; nt < 4; ++nt)
                    bf[nt] = frag(&Bs[0][0], wc + nt * 16 + fr, ks * 4 + fq);
#pragma unroll
                for (int rt = 0; rt < 4; ++rt)
#pragma unroll
                    for (int nt = 0; nt < 4; ++nt)
                        acc[rt][nt] = MFMA16(af[rt], bf[nt], acc[rt][nt]);
            }
        }

        __bf16* tp = Ht + (size_t)c * 262144;
#pragma unroll
        for (int rt = 0; rt < 4; ++rt)
#pragma unroll
            for (int nt = 0; nt < 4; ++nt) {
                const int col = n0 + wc + nt * 16 + fr;
#pragma unroll
                for (int r = 0; r < 4; ++r) {
                    const int row = m0 + wr + rt * 16 + fq * 4 + r;
                    tp[(size_t)row * 512 + col] = (__bf16)acc[rt][nt][r];
                }
            }
    } else {
        const int t = (blockIdx.y - 63) * 16 + blockIdx.x;

        const __bf16* ag = q + (size_t)(t * 128 + wave * 32 + lr) * 512 + cd * 8;
        const __bf16* bg = k + (size_t)(t * 128 + wave * 32 + lr) * 512 + cd * 8;

        for (int kk = 0; kk < 512; kk += 64) {
            __syncthreads();
#pragma unroll
            for (int u = 0; u < 4; ++u) {
                ld16(ag + (size_t)(u * 8) * 512 + kk, al + u * 512);
                ld16(bg + (size_t)(u * 8) * 512 + kk, bl + u * 512);
            }
            __syncthreads();
#pragma unroll
            for (int ks = 0; ks < 2; ++ks) {
                bf16x8 af[4], bf[4];
#pragma unroll
                for (int rt = 0; rt < 4; ++rt)
                    af[rt] = frag(&As[0][0], wr + rt * 16 + fr, ks * 4 + fq);
#pragma unroll
                for (int nt = 0; nt < 4; ++nt)
                    bf[nt] = frag(&Bs[0][0], wc + nt * 16 + fr, ks * 4 + fq);
#pragma unroll
                for (int rt = 0; rt < 4; ++rt)
#pragma unroll
                    for (int nt = 0; nt < 4; ++nt)
                        acc[rt][nt] = MFMA16(af[rt], bf[nt], acc[rt][nt]);
            }
        }

        __bf16* tp = Sd + (size_t)t * 16384;
#pragma unroll
        for (int rt = 0; rt < 4; ++rt)
#pragma unroll
            for (int nt = 0; nt < 4; ++nt) {
                const int col = wc + nt * 16 + fr;
#pragma unroll
                for (int r = 0; r < 4; ++r) {
                    const int row = wr + rt * 16 + fq * 4 + r;
                    float vv = (col < row) ? acc[rt][nt][r] : 0.f;
                    tp[row * 128 + col] = (__bf16)vv;
                }
            }
    }
}

// ---------------------------------------------------------------------------
// Exclusive prefix over chunk axis: Pt[c] = sum_{c'<c} Ht[c'], fp32 accum.
// 512 blocks x 256 thr, 2 elems/thread (v13-exact).
// ---------------------------------------------------------------------------
__global__ __launch_bounds__(256) void prefix_scan(
    const __bf16* __restrict__ Ht, __bf16* __restrict__ Pt)
{
    const size_t e = ((size_t)blockIdx.x * 256 + threadIdx.x) * 2;
    float a0 = 0.f, a1 = 0.f;
#pragma unroll 9
    for (int c = 0; c < 63; ++c) {
        bf16x2 h = *(const bf16x2*)(Ht + (size_t)c * 262144 + e);
        a0 += (float)h[0]; a1 += (float)h[1];
        bf16x2 p;
        p[0] = (__bf16)a0; p[1] = (__bf16)a1;
        *(bf16x2*)(Pt + (size_t)(c + 1) * 262144 + e) = p;
    }
}

// ---------------------------------------------------------------------------
// Out kernel (v13-exact), block (t, n0):
// Phase B: acc = q_t @ Pt_t (K=512, skipped for t=0)
// Phase C: acc += Sd[t] @ v_t (K=128, both operands staged via ld16)
// Non-atomic fp32 store (block owns its 128x128 tile).
// ---------------------------------------------------------------------------
__global__ __launch_bounds__(256, 3) void out_gemm(
    const __bf16* __restrict__ q, const __bf16* __restrict__ Sd,
    const __bf16* __restrict__ vT, const __bf16* __restrict__ Pt,
    float* __restrict__ out)
{
    __shared__ __align__(16) __bf16 As[128][64];
    __shared__ __align__(16) __bf16 Bs[128][64];

    const int t  = blockIdx.x;
    const int n0 = blockIdx.y * 128;

    const int tid  = threadIdx.x;
    const int wave = tid >> 6, lane = tid & 63;
    const int fr = lane & 15, fq = lane >> 4;
    const int wr = (wave >> 1) * 64, wc = (wave & 1) * 64;
    const int lr = lane >> 3;
    const int cd = (lane & 7) ^ lr;
    const int srow = wave * 32 + lr;

    f32x4 acc[4][4];
#pragma unroll
    for (int a = 0; a < 4; ++a)
#pragma unroll
        for (int b = 0; b < 4; ++b) acc[a][b] = f32x4{0.f, 0.f, 0.f, 0.f};

    __bf16* al = &As[wave * 32][0];
    __bf16* bl = &Bs[wave * 32][0];

    // ---- Phase B: inter, acc = q_t @ Pt_t, K=512 ----
    if (t > 0) {
        const __bf16* ag = q + (size_t)(t * 128 + srow) * 512 + cd * 8;
        const __bf16* bg2 = Pt + (size_t)t * 262144
                          + (size_t)(n0 + srow) * 512 + cd * 8;
        for (int kk = 0; kk < 512; kk += 64) {
            __syncthreads();
#pragma unroll
            for (int u = 0; u < 4; ++u) {
                ld16(ag + (size_t)(u * 8) * 512 + kk, al + u * 512);
                ld16(bg2 + (size_t)(u * 8) * 512 + kk, bl + u * 512);
            }
            __syncthreads();
#pragma unroll
            for (int ks = 0; ks < 2; ++ks) {
                bf16x8 af[4], bf[4];
#pragma unroll
                for (int rt = 0; rt < 4; ++rt)
                    af[rt] = frag(&As[0][0], wr + rt * 16 + fr, ks * 4 + fq);
#pragma unroll
                for (int nt = 0; nt < 4; ++nt)
                    bf[nt] = frag(&Bs[0][0], wc + nt * 16 + fr, ks * 4 + fq);
#pragma unroll
                for (int rt = 0; rt < 4; ++rt)
#pragma unroll
                    for (int nt = 0; nt < 4; ++nt)
                        acc[rt][nt] = MFMA16(af[rt], bf[nt], acc[rt][nt]);
            }
        }
    }

    // ---- Phase C: acc += Sd[t] @ v_t, K=128 (both staged via ld16) ----
    const __bf16* at3 = Sd + (size_t)t * 16384 + (size_t)srow * 128 + cd * 8;
    const __bf16* bg3 = vT + (size_t)(n0 + srow) * 8192 + t * 128 + cd * 8;
    for (int kk = 0; kk < 128; kk += 64) {
        __syncthreads();
#pragma unroll
        for (int u = 0; u < 4; ++u) {
            ld16(at3 + (size_t)(u * 8) * 128 + kk, al + u * 512);
            ld16(bg3 + (size_t)(u * 8) * 8192 + kk, bl + u * 512);
        }
        __syncthreads();
#pragma unroll
        for (int ks = 0; ks < 2; ++ks) {
            bf16x8 af[4], bf[4];
#pragma unroll
            for (int rt = 0; rt < 4; ++rt)
                af[rt] = frag(&As[0][0], wr + rt * 16 + fr, ks * 4 + fq);
#pragma unroll
            for (int nt = 0; nt < 4; ++nt)
                bf[nt] = frag(&Bs[0][0], wc + nt * 16 + fr, ks * 4 + fq);
#pragma unroll
            for (int rt = 0; rt < 4; ++rt)
#pragma unroll
                for (int nt = 0; nt < 4; ++nt)
                    acc[rt][nt] = MFMA16(af[rt], bf[nt], acc[rt][nt]);
        }
    }

    // epilogue: exclusive owner of this 128x128 tile -> plain fp32 store
#pragma unroll
    for (int rt = 0; rt < 4; ++rt)
#pragma unroll
        for (int nt = 0; nt < 4; ++nt) {
            const int col = n0 + wc + nt * 16 + fr;
#pragma unroll
            for (int r = 0; r < 4; ++r) {
                const int row = t * 128 + wr + rt * 16 + fq * 4 + r;
                out[(size_t)row * 512 + col] = acc[rt][nt][r];
            }
        }
}

// ---------------------------------------------------------------------------
extern "C" void kernel_launch(void* const* d_in, const int* in_sizes, int n_in,
                              void* d_out, int out_size, void* d_ws, size_t ws_size,
                              hipStream_t stream) {
    const float* x  = (const float*)d_in[0];
    const float* y  = (const float*)d_in[1];
    const float* Wq = (const float*)d_in[2];
    const float* Wk = (const float*)d_in[3];
    const float* Wv = (const float*)d_in[4];
    float* out = (float*)d_out;

    const size_t QK = (size_t)8192 * 512;       // 4194304
    __bf16* q  = (__bf16*)d_ws;
    __bf16* k  = q + QK;
    __bf16* kT = k + QK;
    __bf16* vT = kT + QK;
    __bf16* Ht  = vT + QK;                      // 16777216-elem region
    __bf16* Pt  = Ht + 16777216;                // 16777216-elem region
    __bf16* wqb = Pt + 16777216;
    __bf16* wkb = wqb + 1048576;
    __bf16* wvb = wkb + 1048576;
    __bf16* Sd = wqb;                           // alias: wqb dead after gemm

    convert_w<<<1536, 256, 0, stream>>>(Wq, Wk, Wv, wqb, wkb, wvb);
    gemm_qkv2<<<dim3(64, 8), 512, 0, stream>>>(x, y, wqb, wkb, wvb, q, k, kT, vT);
    hs_gemm<<<dim3(16, 67), 256, 0, stream>>>(vT, kT, q, k, Ht, Sd);
    prefix_scan<<<512, 256, 0, stream>>>(Ht, Pt);
    out_gemm<<<dim3(64, 4), 256, 0, stream>>>(q, Sd, vT, Pt, out);
}

// Round 15
// 252.791 us; speedup vs baseline: 1.1749x; 1.0136x over previous
//
#include <hip/hip_runtime.h>
#include <hip/hip_bf16.h>

// q = x@Wq^T*scale; k = y@Wk^T; v = y@Wv^T
// out = strict_lower(q@k^T) @ v  -- causal LINEAR attention:
//   out_t = q_t @ P_t + strict_tril(q_t k_t^T) @ v_t,  P_t = sum_{c<t} k_c^T v_c
//
// v19 == v16 (measured best, 251.0us). Final configuration.
// Falsification matrix on the 94us gemm (rounds 3-14): staging mechanism
// (v8/v9/v10), LLC traffic (v10), conflicts (v13: 0), 2-phase (v11/v12),
// occupancy down (v17: 141us) and up (v18: neutral at 4 waves/SIMD),
// locality (v16: +1%), topology (v17: worse). Staged-byte service pins at
// ~9.8 TB/s across all of them -> 1-phase-structure plateau, not HW roofline.
// Session: 336.7 -> 251.0us via linear-attention restructure, dual-B fused
// qkv with direct kT/vT epilogues, deleted convert/transpose passes,
// XCD swizzle, prefix TLP.
// ws (bf16 elems): q[4M] k[4M] kT[4M] vT[4M] | Ht[16M] Pt[16M]
//   wq(->Sd)/wk/wv[1M x3].

typedef __bf16 bf16x8 __attribute__((ext_vector_type(8)));
typedef __bf16 bf16x4 __attribute__((ext_vector_type(4)));
typedef __bf16 bf16x2 __attribute__((ext_vector_type(2)));
typedef float f32x4 __attribute__((ext_vector_type(4)));

#define MFMA16(a, b, c) __builtin_amdgcn_mfma_f32_16x16x32_bf16(a, b, c, 0, 0, 0)

constexpr float SCALE = 0.04419417382415922f; // 1/sqrt(512)

__device__ __forceinline__ void ld16(const void* g, void* l) {
    __builtin_amdgcn_global_load_lds(
        (__attribute__((address_space(1))) void*)g,
        (__attribute__((address_space(3))) void*)l, 16, 0, 0);
}

// bf16 tile frag: data-chunk c (16B) of row r from [128][64] bf16 tile
// (128B rows, 8 slots), slot = c ^ (r&7).
__device__ __forceinline__ bf16x8 frag(const __bf16* base, int r, int c) {
    return *(const bf16x8*)((const char*)base + r * 128 + ((c ^ (r & 7)) * 16));
}

// fp32 tile frag: chunks c0,c0+1 (16B each = 4 floats) of row r from
// [128][64] fp32 tile (256B rows, 16 slots), slot = c ^ (r&15); cvt to bf16x8.
__device__ __forceinline__ bf16x8 fragA32(const float* base, int r, int c0) {
    const char* rowp = (const char*)base + r * 256;
    f32x4 a = *(const f32x4*)(rowp + ((c0 ^ (r & 15)) * 16));
    f32x4 b = *(const f32x4*)(rowp + (((c0 + 1) ^ (r & 15)) * 16));
    bf16x8 o;
    o[0] = (__bf16)a[0]; o[1] = (__bf16)a[1];
    o[2] = (__bf16)a[2]; o[3] = (__bf16)a[3];
    o[4] = (__bf16)b[0]; o[5] = (__bf16)b[1];
    o[6] = (__bf16)b[2]; o[7] = (__bf16)b[3];
    return o;
}

__device__ inline bf16x4 pack4(float4 a) {
    bf16x4 r;
    r[0] = (__bf16)a.x; r[1] = (__bf16)a.y;
    r[2] = (__bf16)a.z; r[3] = (__bf16)a.w;
    return r;
}

// ---------------------------------------------------------------------------
// Weights fp32 -> bf16 only. Wave owns 512 contiguous floats. 6144 waves.
// ---------------------------------------------------------------------------
__global__ __launch_bounds__(256) void convert_w(
    const float* __restrict__ wqf, const float* __restrict__ wkf,
    const float* __restrict__ wvf, __bf16* __restrict__ wqb,
    __bf16* __restrict__ wkb, __bf16* __restrict__ wvb)
{
    const size_t tid = (size_t)blockIdx.x * 256 + threadIdx.x;
    const size_t w = tid >> 6;
    const int lane = (int)(tid & 63);
    size_t f = w * 512;
    const float* src; __bf16* dst;
    if (f < 1048576)      { src = wqf; dst = wqb; }
    else if (f < 2097152) { src = wkf; dst = wkb; f -= 1048576; }
    else                  { src = wvf; dst = wvb; f -= 2097152; }
    const float4* s4 = (const float4*)(src + f);
    float4 a = s4[lane];
    float4 b = s4[64 + lane];
    __bf16* d = dst + f;
    *(bf16x4*)(d + lane * 4)       = pack4(a);
    *(bf16x4*)(d + 256 + lane * 4) = pack4(b);
}

// ---------------------------------------------------------------------------
// Fused q/kv GEMM (v13 structure + XCD swizzle). 512 blocks:
//   ycfg even (q-block):  acc0 = bf16(x_t) @ Wq^T -> qo (SCALE folded)
//   ycfg odd  (kv-block): acc0 = bf16(y_t) @ Wk^T -> ko + kT
//                         acc1 = bf16(y_t) @ Wv^T -> vT  (same staged A!)
// XCD swizzle: lin%8 = XCD owns m-tiles [xcd*8, xcd*8+8) for all 8 ycfgs,
// so the 4 blocks sharing each A-slice are co-resident on one XCD's L2.
// A staged raw fp32 async into [128][64] f32 (16-slot swizzle, c^(r&15));
// fp32->bf16 at frag-read. B staged bf16 (8-slot). 64KB LDS, 2 blocks/CU.
// ---------------------------------------------------------------------------
__global__ __launch_bounds__(256, 2) void gemm_qkv2(
    const float* __restrict__ x, const float* __restrict__ y,
    const __bf16* __restrict__ wq, const __bf16* __restrict__ wk,
    const __bf16* __restrict__ wv, __bf16* __restrict__ qo,
    __bf16* __restrict__ ko, __bf16* __restrict__ kT,
    __bf16* __restrict__ vT)
{
    constexpr int K = 2048, N = 512;
    __shared__ __align__(16) float  Asf[128][64];     // 32 KB
    __shared__ __align__(16) __bf16 Bs[2][128][64];   // 32 KB

    // XCD-aware remap (bijective on 512 blocks; lin%8 assumed = XCD)
    const int lin  = blockIdx.y * 64 + blockIdx.x;
    const int xcd  = lin & 7;
    const int idx  = lin >> 3;
    const int mb   = xcd * 8 + (idx & 7);   // m-tile 0..63
    const int ycfg = idx >> 3;              // 0..7

    const bool iskv = (ycfg & 1) != 0;
    const float* A = iskv ? y : x;
    const __bf16* B0 = iskv ? wk : wq;

    const int tid  = threadIdx.x;
    const int wave = tid >> 6, lane = tid & 63;
    const int fr = lane & 15, fq = lane >> 4;
    const int m0 = mb * 128, n0 = (ycfg >> 1) * 128;
    const int wr = (wave >> 1) * 64, wc = (wave & 1) * 64;
    const int lr = lane >> 3;            // B staging: row within 8-row group
    const int cd = (lane & 7) ^ lr;      // B staging: swizzled chunk
    const int lr4 = lane >> 4;           // A staging: row within 4-row group
    const int cl  = lane & 15;           // A staging: LDS slot (16 per row)

    f32x4 acc0[4][4], acc1[4][4];
#pragma unroll
    for (int a = 0; a < 4; ++a)
#pragma unroll
        for (int b = 0; b < 4; ++b) {
            acc0[a][b] = f32x4{0.f, 0.f, 0.f, 0.f};
            acc1[a][b] = f32x4{0.f, 0.f, 0.f, 0.f};
        }

    const __bf16* bg0 = B0 + (size_t)(n0 + wave * 32 + lr) * K + cd * 8;
    const __bf16* bg1 = wv + (size_t)(n0 + wave * 32 + lr) * K + cd * 8;
    float*  alf = &Asf[wave * 32][0];
    __bf16* bl0 = &Bs[0][wave * 32][0];
    __bf16* bl1 = &Bs[1][wave * 32][0];
    const float* ag0 = A + (size_t)(m0 + wave * 32 + lr4) * K;

    for (int kk = 0; kk < K; kk += 64) {
        __syncthreads();                 // prev step's frag reads done
#pragma unroll
        for (int u = 0; u < 4; ++u)
            ld16(bg0 + (size_t)(u * 8) * K + kk, bl0 + u * 512);
        if (iskv) {
#pragma unroll
            for (int u = 0; u < 4; ++u)
                ld16(bg1 + (size_t)(u * 8) * K + kk, bl1 + u * 512);
        }
#pragma unroll
        for (int u = 0; u < 8; ++u) {
            const int rw = u * 4 + lr4;          // row within wave group
            const int c  = cl ^ (rw & 15);       // source data chunk
            ld16(ag0 + (size_t)(u * 4) * K + kk + c * 4, alf + u * 256);
        }
        __syncthreads();                 // drains vmcnt: tiles visible
#pragma unroll
        for (int ks = 0; ks < 2; ++ks) {
            bf16x8 af[4], bf[4];
#pragma unroll
            for (int rt = 0; rt < 4; ++rt)
                af[rt] = fragA32(&Asf[0][0], wr + rt * 16 + fr, ks * 8 + fq * 2);
#pragma unroll
            for (int nt = 0; nt < 4; ++nt)
                bf[nt] = frag(&Bs[0][0][0], wc + nt * 16 + fr, ks * 4 + fq);
#pragma unroll
            for (int rt = 0; rt < 4; ++rt)
#pragma unroll
                for (int nt = 0; nt < 4; ++nt)
                    acc0[rt][nt] = MFMA16(af[rt], bf[nt], acc0[rt][nt]);
            if (iskv) {
                bf16x8 bg[4];
#pragma unroll
                for (int nt = 0; nt < 4; ++nt)
                    bg[nt] = frag(&Bs[1][0][0], wc + nt * 16 + fr, ks * 4 + fq);
#pragma unroll
                for (int rt = 0; rt < 4; ++rt)
#pragma unroll
                    for (int nt = 0; nt < 4; ++nt)
                        acc1[rt][nt] = MFMA16(af[rt], bg[nt], acc1[rt][nt]);
            }
        }
    }

    if (!iskv) {
#pragma unroll
        for (int rt = 0; rt < 4; ++rt)
#pragma unroll
            for (int nt = 0; nt < 4; ++nt) {
                const int col = n0 + wc + nt * 16 + fr;
#pragma unroll
                for (int r = 0; r < 4; ++r) {
                    const int row = m0 + wr + rt * 16 + fq * 4 + r;
                    qo[(size_t)row * N + col] = (__bf16)(acc0[rt][nt][r] * SCALE);
                }
            }
    } else {
#pragma unroll
        for (int rt = 0; rt < 4; ++rt)
#pragma unroll
            for (int nt = 0; nt < 4; ++nt) {
                const int col  = n0 + wc + nt * 16 + fr;
                const int row0 = m0 + wr + rt * 16 + fq * 4;
                bf16x4 k4, v4;
#pragma unroll
                for (int r = 0; r < 4; ++r) {
                    k4[r] = (__bf16)acc0[rt][nt][r];
                    v4[r] = (__bf16)acc1[rt][nt][r];
                    ko[(size_t)(row0 + r) * N + col] = k4[r];
                }
                *(bf16x4*)(kT + (size_t)col * 8192 + row0) = k4;
                *(bf16x4*)(vT + (size_t)col * 8192 + row0) = v4;
            }
    }
}

// ---------------------------------------------------------------------------
// Merged H + diagonal-S launch (v13-exact), grid (16, 67):
//  y <  63: Ht[c][n][d] = (vT_c @ kT_c^T), c = y, K=128
//  y >= 63: Sd[t] = strict_tril(q_t @ k_t^T), t = (y-63)*16 + x, K=512
// ---------------------------------------------------------------------------
__global__ __launch_bounds__(256, 3) void hs_gemm(
    const __bf16* __restrict__ vT, const __bf16* __restrict__ kT,
    const __bf16* __restrict__ q, const __bf16* __restrict__ k,
    __bf16* __restrict__ Ht, __bf16* __restrict__ Sd)
{
    __shared__ __align__(16) __bf16 As[128][64];
    __shared__ __align__(16) __bf16 Bs[128][64];

    const int tid  = threadIdx.x;
    const int wave = tid >> 6, lane = tid & 63;
    const int fr = lane & 15, fq = lane >> 4;
    const int wr = (wave >> 1) * 64, wc = (wave & 1) * 64;
    const int lr = lane >> 3;
    const int cd = (lane & 7) ^ lr;

    f32x4 acc[4][4];
#pragma unroll
    for (int a = 0; a < 4; ++a)
#pragma unroll
        for (int b = 0; b < 4; ++b) acc[a][b] = f32x4{0.f, 0.f, 0.f, 0.f};

    __bf16* al = &As[wave * 32][0];
    __bf16* bl = &Bs[wave * 32][0];

    if (blockIdx.y < 63) {
        const int c  = blockIdx.y;
        const int m0 = (blockIdx.x & 3) * 128;
        const int n0 = (blockIdx.x >> 2) * 128;

        const __bf16* ag = vT + (size_t)(m0 + wave * 32 + lr) * 8192 + c * 128 + cd * 8;
        const __bf16* bg = kT + (size_t)(n0 + wave * 32 + lr) * 8192 + c * 128 + cd * 8;

        for (int kk = 0; kk < 128; kk += 64) {
            __syncthreads();
#pragma unroll
            for (int u = 0; u < 4; ++u) {
                ld16(ag + (size_t)(u * 8) * 8192 + kk, al + u * 512);
                ld16(bg + (size_t)(u * 8) * 8192 + kk, bl + u * 512);
            }
            __syncthreads();
#pragma unroll
            for (int ks = 0; ks < 2; ++ks) {
                bf16x8 af[4], bf[4];
#pragma unroll
                for (int rt = 0; rt < 4; ++rt)
                    af[rt] = frag(&As[0][0], wr + rt * 16 + fr, ks * 4 + fq);
#pragma unroll
                for (int nt = 0; nt < 4; ++nt)
                    bf[nt] = frag(&Bs[0][0], wc + nt * 16 + fr, ks * 4 + fq);
#pragma unroll
                for (int rt = 0; rt < 4; ++rt)
#pragma unroll
                    for (int nt = 0; nt < 4; ++nt)
                        acc[rt][nt] = MFMA16(af[rt], bf[nt], acc[rt][nt]);
            }
        }

        __bf16* tp = Ht + (size_t)c * 262144;
#pragma unroll
        for (int rt = 0; rt < 4; ++rt)
#pragma unroll
            for (int nt = 0; nt < 4; ++nt) {
                const int col = n0 + wc + nt * 16 + fr;
#pragma unroll
                for (int r = 0; r < 4; ++r) {
                    const int row = m0 + wr + rt * 16 + fq * 4 + r;
                    tp[(size_t)row * 512 + col] = (__bf16)acc[rt][nt][r];
                }
            }
    } else {
        const int t = (blockIdx.y - 63) * 16 + blockIdx.x;

        const __bf16* ag = q + (size_t)(t * 128 + wave * 32 + lr) * 512 + cd * 8;
        const __bf16* bg = k + (size_t)(t * 128 + wave * 32 + lr) * 512 + cd * 8;

        for (int kk = 0; kk < 512; kk += 64) {
            __syncthreads();
#pragma unroll
            for (int u = 0; u < 4; ++u) {
                ld16(ag + (size_t)(u * 8) * 512 + kk, al + u * 512);
                ld16(bg + (size_t)(u * 8) * 512 + kk, bl + u * 512);
            }
            __syncthreads();
#pragma unroll
            for (int ks = 0; ks < 2; ++ks) {
                bf16x8 af[4], bf[4];
#pragma unroll
                for (int rt = 0; rt < 4; ++rt)
                    af[rt] = frag(&As[0][0], wr + rt * 16 + fr, ks * 4 + fq);
#pragma unroll
                for (int nt = 0; nt < 4; ++nt)
                    bf[nt] = frag(&Bs[0][0], wc + nt * 16 + fr, ks * 4 + fq);
#pragma unroll
                for (int rt = 0; rt < 4; ++rt)
#pragma unroll
                    for (int nt = 0; nt < 4; ++nt)
                        acc[rt][nt] = MFMA16(af[rt], bf[nt], acc[rt][nt]);
            }
        }

        __bf16* tp = Sd + (size_t)t * 16384;
#pragma unroll
        for (int rt = 0; rt < 4; ++rt)
#pragma unroll
            for (int nt = 0; nt < 4; ++nt) {
                const int col = wc + nt * 16 + fr;
#pragma unroll
                for (int r = 0; r < 4; ++r) {
                    const int row = wr + rt * 16 + fq * 4 + r;
                    float vv = (col < row) ? acc[rt][nt][r] : 0.f;
                    tp[row * 128 + col] = (__bf16)vv;
                }
            }
    }
}

// ---------------------------------------------------------------------------
// Exclusive prefix over chunk axis: Pt[c] = sum_{c'<c} Ht[c'], fp32 accum.
// 512 blocks x 256 thr, 2 elems/thread (v13-exact).
// ---------------------------------------------------------------------------
__global__ __launch_bounds__(256) void prefix_scan(
    const __bf16* __restrict__ Ht, __bf16* __restrict__ Pt)
{
    const size_t e = ((size_t)blockIdx.x * 256 + threadIdx.x) * 2;
    float a0 = 0.f, a1 = 0.f;
#pragma unroll 9
    for (int c = 0; c < 63; ++c) {
        bf16x2 h = *(const bf16x2*)(Ht + (size_t)c * 262144 + e);
        a0 += (float)h[0]; a1 += (float)h[1];
        bf16x2 p;
        p[0] = (__bf16)a0; p[1] = (__bf16)a1;
        *(bf16x2*)(Pt + (size_t)(c + 1) * 262144 + e) = p;
    }
}

// ---------------------------------------------------------------------------
// Out kernel (v13-exact), block (t, n0):
// Phase B: acc = q_t @ Pt_t (K=512, skipped for t=0)
// Phase C: acc += Sd[t] @ v_t (K=128, both operands staged via ld16)
// Non-atomic fp32 store (block owns its 128x128 tile).
// ---------------------------------------------------------------------------
__global__ __launch_bounds__(256, 3) void out_gemm(
    const __bf16* __restrict__ q, const __bf16* __restrict__ Sd,
    const __bf16* __restrict__ vT, const __bf16* __restrict__ Pt,
    float* __restrict__ out)
{
    __shared__ __align__(16) __bf16 As[128][64];
    __shared__ __align__(16) __bf16 Bs[128][64];

    const int t  = blockIdx.x;
    const int n0 = blockIdx.y * 128;

    const int tid  = threadIdx.x;
    const int wave = tid >> 6, lane = tid & 63;
    const int fr = lane & 15, fq = lane >> 4;
    const int wr = (wave >> 1) * 64, wc = (wave & 1) * 64;
    const int lr = lane >> 3;
    const int cd = (lane & 7) ^ lr;
    const int srow = wave * 32 + lr;

    f32x4 acc[4][4];
#pragma unroll
    for (int a = 0; a < 4; ++a)
#pragma unroll
        for (int b = 0; b < 4; ++b) acc[a][b] = f32x4{0.f, 0.f, 0.f, 0.f};

    __bf16* al = &As[wave * 32][0];
    __bf16* bl = &Bs[wave * 32][0];

    // ---- Phase B: inter, acc = q_t @ Pt_t, K=512 ----
    if (t > 0) {
        const __bf16* ag = q + (size_t)(t * 128 + srow) * 512 + cd * 8;
        const __bf16* bg2 = Pt + (size_t)t * 262144
                          + (size_t)(n0 + srow) * 512 + cd * 8;
        for (int kk = 0; kk < 512; kk += 64) {
            __syncthreads();
#pragma unroll
            for (int u = 0; u < 4; ++u) {
                ld16(ag + (size_t)(u * 8) * 512 + kk, al + u * 512);
                ld16(bg2 + (size_t)(u * 8) * 512 + kk, bl + u * 512);
            }
            __syncthreads();
#pragma unroll
            for (int ks = 0; ks < 2; ++ks) {
                bf16x8 af[4], bf[4];
#pragma unroll
                for (int rt = 0; rt < 4; ++rt)
                    af[rt] = frag(&As[0][0], wr + rt * 16 + fr, ks * 4 + fq);
#pragma unroll
                for (int nt = 0; nt < 4; ++nt)
                    bf[nt] = frag(&Bs[0][0], wc + nt * 16 + fr, ks * 4 + fq);
#pragma unroll
                for (int rt = 0; rt < 4; ++rt)
#pragma unroll
                    for (int nt = 0; nt < 4; ++nt)
                        acc[rt][nt] = MFMA16(af[rt], bf[nt], acc[rt][nt]);
            }
        }
    }

    // ---- Phase C: acc += Sd[t] @ v_t, K=128 (both staged via ld16) ----
    const __bf16* at3 = Sd + (size_t)t * 16384 + (size_t)srow * 128 + cd * 8;
    const __bf16* bg3 = vT + (size_t)(n0 + srow) * 8192 + t * 128 + cd * 8;
    for (int kk = 0; kk < 128; kk += 64) {
        __syncthreads();
#pragma unroll
        for (int u = 0; u < 4; ++u) {
            ld16(at3 + (size_t)(u * 8) * 128 + kk, al + u * 512);
            ld16(bg3 + (size_t)(u * 8) * 8192 + kk, bl + u * 512);
        }
        __syncthreads();
#pragma unroll
        for (int ks = 0; ks < 2; ++ks) {
            bf16x8 af[4], bf[4];
#pragma unroll
            for (int rt = 0; rt < 4; ++rt)
                af[rt] = frag(&As[0][0], wr + rt * 16 + fr, ks * 4 + fq);
#pragma unroll
            for (int nt = 0; nt < 4; ++nt)
                bf[nt] = frag(&Bs[0][0], wc + nt * 16 + fr, ks * 4 + fq);
#pragma unroll
            for (int rt = 0; rt < 4; ++rt)
#pragma unroll
                for (int nt = 0; nt < 4; ++nt)
                    acc[rt][nt] = MFMA16(af[rt], bf[nt], acc[rt][nt]);
        }
    }

    // epilogue: exclusive owner of this 128x128 tile -> plain fp32 store
#pragma unroll
    for (int rt = 0; rt < 4; ++rt)
#pragma unroll
        for (int nt = 0; nt < 4; ++nt) {
            const int col = n0 + wc + nt * 16 + fr;
#pragma unroll
            for (int r = 0; r < 4; ++r) {
                const int row = t * 128 + wr + rt * 16 + fq * 4 + r;
                out[(size_t)row * 512 + col] = acc[rt][nt][r];
            }
        }
}

// ---------------------------------------------------------------------------
extern "C" void kernel_launch(void* const* d_in, const int* in_sizes, int n_in,
                              void* d_out, int out_size, void* d_ws, size_t ws_size,
                              hipStream_t stream) {
    const float* x  = (const float*)d_in[0];
    const float* y  = (const float*)d_in[1];
    const float* Wq = (const float*)d_in[2];
    const float* Wk = (const float*)d_in[3];
    const float* Wv = (const float*)d_in[4];
    float* out = (float*)d_out;

    const size_t QK = (size_t)8192 * 512;       // 4194304
    __bf16* q  = (__bf16*)d_ws;
    __bf16* k  = q + QK;
    __bf16* kT = k + QK;
    __bf16* vT = kT + QK;
    __bf16* Ht  = vT + QK;                      // 16777216-elem region
    __bf16* Pt  = Ht + 16777216;                // 16777216-elem region
    __bf16* wqb = Pt + 16777216;
    __bf16* wkb = wqb + 1048576;
    __bf16* wvb = wkb + 1048576;
    __bf16* Sd = wqb;                           // alias: wqb dead after gemm

    convert_w<<<1536, 256, 0, stream>>>(Wq, Wk, Wv, wqb, wkb, wvb);
    gemm_qkv2<<<dim3(64, 8), 256, 0, stream>>>(x, y, wqb, wkb, wvb, q, k, kT, vT);
    hs_gemm<<<dim3(16, 67), 256, 0, stream>>>(vT, kT, q, k, Ht, Sd);
    prefix_scan<<<512, 256, 0, stream>>>(Ht, Pt);
    out_gemm<<<dim3(64, 4), 256, 0, stream>>>(q, Sd, vT, Pt, out);
}